// Round 2
// baseline (56029.816 us; speedup 1.0000x reference)
//
#include <hip/hip_runtime.h>
#include <cmath>

// MARNN scan v5 — persistent fused scan kernel, hardened.
// v4 (never ran: container died) put its grid-barrier counter ONE WORD past
// the exact end of the v3 workspace layout — likely OOB page fault. v5 keeps
// barrier state in __device__ module globals (zero workspace growth) and uses
// a fast-fail watchdog (~50 ms) + global abort flag so any barrier failure
// surfaces as a wrong-answer test failure, never a hang.
// Phase bodies are VERBATIM transplants of v3's k_gates1/k_pre_gemm/k_epi:
//   P1 (blocks 0..79):  argmax + h_ent gather + gates1 GEMM (K-split x2)
//   P2 (blocks 0..135): pre GEMM with on-the-fly gating (K-split x2)
//   P3 (blocks 0..63):  epilogue (LSTM cell, outputs, wv/head GEMVs fp64,
//                       hmem update, score(t+1) c-contribution)
// Scores for all t precomputed in fp64 by k_score (unchanged).

#define TT 256
#define BB 256
#define XD 256
#define HD 512
#define RD 128
#define MD 128
#define N1 640    // R + H      (gates1 width)
#define NP 2176   // R + 4H     (pre width)

// ---- ws layout (float offsets) — 5,964,288 floats, identical to v3 ----
#define OFF_C     0u         // cbuf  [B,H]
#define OFF_HMEM  131072u    // hmem  [B,M,R]
#define OFF_HENT  4325376u   // h_ent [B,R]
#define OFF_SEL   4358144u   // selbuf[B] int
#define OFF_FXT   4358400u   // fcxT  [256,128]  fc_w[:, :256]^T
#define OFF_TWT   4391168u   // transT[512,128]  trans_w^T
#define OFF_FWT   4456704u   // fcwcT [512,128]  fc_w[:,256:768]^T
#define OFF_HEAD0 4522240u   // head0 [M] double
#define OFF_G1P   4522496u   // g1 partials  float [2][B,N1]
#define OFF_PREP  4850176u   // pre partials float [2][B,NP]

#define NBLK 136

// barrier state lives in module globals — NOT in the workspace
__device__ unsigned int g_cnt;
__device__ unsigned int g_abrt;

__device__ __forceinline__ float sigm(float z){ return 1.0f/(1.0f + expf(-z)); }
__device__ __forceinline__ float4 ld4(const float* p){ return *(const float4*)p; }

// ---------- init: state, transposes, head0 (fp64), barrier reset ----------
__global__ __launch_bounds__(256)
void k_pre(const float* __restrict__ fc_w, const float* __restrict__ trans_w,
           const float* __restrict__ c_bias, const float* __restrict__ hmem_bias,
           float* __restrict__ ws)
{
  float*  cbuf   = ws + OFF_C;
  float*  hmem   = ws + OFF_HMEM;
  float*  fcxT   = ws + OFF_FXT;
  float*  transT = ws + OFF_TWT;
  float*  fcwcT  = ws + OFF_FWT;
  double* head0d = (double*)(ws + OFF_HEAD0);

  const int gt = blockIdx.x*256 + threadIdx.x, GT = gridDim.x*256;
  if (gt == 0) { g_cnt = 0u; g_abrt = 0u; }           // reset scan barrier
  for (int i = gt; i < BB*HD;    i += GT) cbuf[i] = (float)tanh((double)c_bias[i & 511]);
  for (int i = gt; i < BB*MD*RD; i += GT) hmem[i] = hmem_bias[i & (MD*RD - 1)];
  for (int i = gt; i < XD*128;   i += GT) { int k=i>>7, m=i&127; fcxT[i]  = fc_w[(size_t)m*768 + k]; }
  for (int i = gt; i < HD*128;   i += GT) { int k=i>>7, o=i&127; transT[i] = trans_w[(size_t)o*512 + k];
                                            fcwcT[i]  = fc_w[(size_t)o*768 + 256 + k]; }
  if (blockIdx.x == 0 && threadIdx.x < 128) {
    double a = 0.0;
    for (int k = 0; k < 512; ++k)
      a += tanh((double)c_bias[k]) * (double)fc_w[(size_t)threadIdx.x*768 + 256 + k];
    head0d[threadIdx.x] = a;
  }
}

// ---------- score: out[t,b,512+m] = fp64(x-part head + fc_b + gumbel) ----------
__global__ __launch_bounds__(256)
void k_score(const float* __restrict__ x, const float* __restrict__ noise,
             const float* __restrict__ fc_b, const float* __restrict__ ws_fcxT,
             float* __restrict__ out)
{
  __shared__ float xs[16*256];
  const int tid = threadIdx.x;
  const int rbase = blockIdx.x * 16;           // 4096 blocks x 16 rows
  for (int i = tid; i < 16*64; i += 256) {
    int row = i >> 6, kq = (i & 63) << 2;
    *(float4*)&xs[row*256 + kq] = ld4(x + (size_t)(rbase + row)*XD + kq);
  }
  __syncthreads();
  const int m = tid & 127, r0 = (tid >> 7) * 8;
  double acc[8] = {};
  for (int k = 0; k < 256; ++k) {
    double wk = (double)ws_fcxT[k*128 + m];
    #pragma unroll
    for (int r = 0; r < 8; ++r) acc[r] += wk * (double)xs[(r0+r)*256 + k];
  }
  #pragma unroll
  for (int r = 0; r < 8; ++r) {
    size_t grow = (size_t)rbase + r0 + r;
    double g   = (double)noise[grow*MD + m];
    double gum = -log(1e-20 - log(1e-20 + g));
    out[grow*640 + 512 + m] = (float)(acc[r] + (double)fc_b[m] + gum);
  }
}

// ---------- persistent scan kernel ----------
__global__ __launch_bounds__(256)
void k_scan(const float* __restrict__ x, const float* __restrict__ W_full,
            const float* __restrict__ W_full1, const float* __restrict__ bias,
            const float* __restrict__ bias1, const float* __restrict__ trans_b,
            float* __restrict__ out, float* __restrict__ ws)
{
  __shared__ float As[16][68];
  __shared__ float Bs[16][128];     // P1 uses cols 0..63, P2 uses 0..127
  __shared__ int   sel[64];
  __shared__ float smc[4*512];
  __shared__ float smwv[4*128];
  __shared__ int   s_bad;

  const int tid = threadIdx.x, bid = blockIdx.x;
  unsigned int bars = 0;

  // device-scope grid barrier: monotonic counter, fast-fail watchdog + abort
  auto gbar = [&]() -> bool {
    ++bars;
    const unsigned int target = (unsigned int)NBLK * bars;
    __syncthreads();
    if (tid == 0) {
      __threadfence();   // release: make this block's writes agent-visible
      __hip_atomic_fetch_add(&g_cnt, 1u, __ATOMIC_RELEASE, __HIP_MEMORY_SCOPE_AGENT);
      long long t0 = __builtin_amdgcn_s_memrealtime();
      int bad = 0;
      while (__hip_atomic_load(&g_cnt, __ATOMIC_ACQUIRE, __HIP_MEMORY_SCOPE_AGENT) < target) {
        __builtin_amdgcn_s_sleep(8);
        if (__hip_atomic_load(&g_abrt, __ATOMIC_RELAXED, __HIP_MEMORY_SCOPE_AGENT) != 0u) { bad = 1; break; }
        if (__builtin_amdgcn_s_memrealtime() - t0 > 5000000LL) {   // ~50 ms
          __hip_atomic_store(&g_abrt, 1u, __ATOMIC_RELAXED, __HIP_MEMORY_SCOPE_AGENT);
          bad = 1; break;
        }
      }
      __threadfence();   // acquire: see other blocks' writes
      s_bad = bad;
    }
    __syncthreads();
    return s_bad == 0;
  };

  for (int t = 0; t < TT; ++t) {
    // ================= P1: argmax + gather + gates1 GEMM (blocks 0..79) =================
    if (bid < 80) {
      const int rt = bid & 3, ct = (bid >> 2) % 10, kc = bid / 40;
      const int r0 = rt*64, n0 = ct*64, kbeg = kc*448;
      const float* cbuf = ws + OFF_C;
      const float* hmem = ws + OFF_HMEM;
      float*  hent  = ws + OFF_HENT;
      int*    selb  = (int*)(ws + OFF_SEL);
      double* head0d= (double*)(ws + OFF_HEAD0);
      float*  g1p   = ws + OFF_G1P + (size_t)kc*BB*N1;

      if (kc == 1) {                               // this K-range touches h_entry
        if (tid < 64) {
          const float* sc = out + ((size_t)t*BB + r0 + tid)*640 + 512;
          int bi = 0;
          if (t == 0) { double best = -1e300;
            for (int m = 0; m < 128; ++m) { double v = (double)sc[m] + head0d[m]; if (v > best) { best = v; bi = m; } } }
          else { float best = -3.4e38f;
            for (int m = 0; m < 128; ++m) { float v = sc[m]; if (v > best) { best = v; bi = m; } } }
          sel[tid] = bi;
        }
        __syncthreads();
        if (ct == 0) {                             // designated writer per row-group
          if (tid < 64) selb[r0 + tid] = sel[tid];
          for (int idx = tid; idx < 64*128; idx += 256) {
            int row = idx >> 7, rr = idx & 127;
            hent[(size_t)(r0+row)*RD + rr] = hmem[((size_t)(r0+row)*MD + sel[row])*RD + rr];
          }
        }
      }

      float  acc[4][4] = {};
      double accd[4][4] = {};
      const int tx = tid & 15, ty = tid >> 4;
      const int arow = tid >> 2, akq = (tid & 3) << 2;
      const int bkk = tid >> 4, bnq = (tid & 15) << 2;

      for (int k0 = kbeg; k0 < kbeg + 448; k0 += 16) {
        __syncthreads();
        { // stage A (k-major transpose)
          int b = r0 + arow, k = k0 + akq;
          float4 v;
          if (k < XD)           v = ld4(x + ((size_t)t*BB + b)*XD + k);
          else if (k < XD + HD) v = ld4(cbuf + (size_t)b*HD + (k - XD));
          else                  v = ld4(hmem + ((size_t)b*MD + sel[arow])*RD + (k - (XD+HD)));
          As[akq+0][arow] = v.x; As[akq+1][arow] = v.y;
          As[akq+2][arow] = v.z; As[akq+3][arow] = v.w;
        }
        *(float4*)&Bs[bkk][bnq] = ld4(W_full1 + (size_t)(k0 + bkk)*N1 + n0 + bnq);
        __syncthreads();
        #pragma unroll
        for (int kk = 0; kk < 16; ++kk) {
          float a[4], b[4];
          *(float4*)a = ld4(&As[kk][ty*4]);
          *(float4*)b = ld4(&Bs[kk][tx*4]);
          #pragma unroll
          for (int i = 0; i < 4; ++i)
            #pragma unroll
            for (int j = 0; j < 4; ++j)
              acc[i][j] = fmaf(a[i], b[j], acc[i][j]);
          if ((kk & 7) == 7) {                     // fp64 fold every 8 k
            #pragma unroll
            for (int i = 0; i < 4; ++i)
              #pragma unroll
              for (int j = 0; j < 4; ++j) { accd[i][j] += (double)acc[i][j]; acc[i][j] = 0.f; }
          }
        }
      }
      #pragma unroll
      for (int i = 0; i < 4; ++i)
        #pragma unroll
        for (int j = 0; j < 4; ++j)
          g1p[(size_t)(r0 + ty*4 + i)*N1 + n0 + tx*4 + j] = (float)accd[i][j];
    }
    if (!gbar()) return;

    // ================= P2: pre GEMM with on-the-fly gating (all 136 blocks) =================
    {
      const int rt = bid & 3, ct = (bid >> 2) % 17, kc = bid / 68;
      const int r0 = rt*64, n0 = ct*128, kbeg = kc*448;
      const float* cbuf = ws + OFF_C;
      const float* hent = ws + OFF_HENT;
      const float* g1p0 = ws + OFF_G1P;
      const float* g1p1 = g1p0 + (size_t)BB*N1;
      float* prep = ws + OFF_PREP + (size_t)kc*BB*NP;

      float  acc[4][8] = {};
      double accd[4][8] = {};
      const int tx = tid & 15, ty = tid >> 4;
      const int arow = tid >> 2, akq = (tid & 3) << 2;

      for (int k0 = kbeg; k0 < kbeg + 448; k0 += 16) {
        __syncthreads();
        { // stage A with gating applied at load time
          int b = r0 + arow, k = k0 + akq;
          float4 v;
          if (k < XD) v = ld4(x + ((size_t)t*BB + b)*XD + k);
          else if (k < XD + HD) {
            int j = k - XD;
            v = ld4(cbuf + (size_t)b*HD + j);
            float4 p0 = ld4(g1p0 + (size_t)b*N1 + j);
            float4 p1 = ld4(g1p1 + (size_t)b*N1 + j);
            float4 bb = ld4(bias1 + j);
            v.x *= sigm(p0.x + p1.x + bb.x);
            v.y *= sigm(p0.y + p1.y + bb.y);
            v.z *= sigm(p0.z + p1.z + bb.z);
            v.w *= sigm(p0.w + p1.w + bb.w);
          } else {
            int j = k - (XD + HD);
            v = ld4(hent + (size_t)b*RD + j);
            float4 p0 = ld4(g1p0 + (size_t)b*N1 + 512 + j);
            float4 p1 = ld4(g1p1 + (size_t)b*N1 + 512 + j);
            float4 bb = ld4(bias1 + 512 + j);
            v.x *= sigm(p0.x + p1.x + bb.x);
            v.y *= sigm(p0.y + p1.y + bb.y);
            v.z *= sigm(p0.z + p1.z + bb.z);
            v.w *= sigm(p0.w + p1.w + bb.w);
          }
          As[akq+0][arow] = v.x; As[akq+1][arow] = v.y;
          As[akq+2][arow] = v.z; As[akq+3][arow] = v.w;
        }
        #pragma unroll
        for (int rep = 0; rep < 2; ++rep) {
          int idx = tid + rep*256, kk = idx >> 5, nq = (idx & 31) << 2;
          *(float4*)&Bs[kk][nq] = ld4(W_full + (size_t)(k0 + kk)*NP + n0 + nq);
        }
        __syncthreads();
        #pragma unroll
        for (int kk = 0; kk < 16; ++kk) {
          float a[4], b[8];
          *(float4*)a = ld4(&As[kk][ty*4]);
          *(float4*)&b[0] = ld4(&Bs[kk][tx*8]);
          *(float4*)&b[4] = ld4(&Bs[kk][tx*8 + 4]);
          #pragma unroll
          for (int i = 0; i < 4; ++i)
            #pragma unroll
            for (int j = 0; j < 8; ++j)
              acc[i][j] = fmaf(a[i], b[j], acc[i][j]);
          if ((kk & 7) == 7) {
            #pragma unroll
            for (int i = 0; i < 4; ++i)
              #pragma unroll
              for (int j = 0; j < 8; ++j) { accd[i][j] += (double)acc[i][j]; acc[i][j] = 0.f; }
          }
        }
      }
      #pragma unroll
      for (int i = 0; i < 4; ++i)
        #pragma unroll
        for (int j = 0; j < 8; ++j)
          prep[(size_t)(r0 + ty*4 + i)*NP + n0 + tx*8 + j] = (float)accd[i][j];
    }
    if (!gbar()) return;

    // ================= P3: epilogue (blocks 0..63, 4 batch rows each) =================
    if (bid < 64) {
      const int b0 = bid*4;
      float*  cbuf   = ws + OFF_C;
      float*  hmem   = ws + OFF_HMEM;
      float*  hent   = ws + OFF_HENT;
      int*    selb   = (int*)(ws + OFF_SEL);
      float*  transT = ws + OFF_TWT;
      float*  fcwcT  = ws + OFF_FWT;
      const float* prep0 = ws + OFF_PREP;
      const float* prep1 = prep0 + (size_t)BB*NP;

      for (int idx = tid; idx < 4*512; idx += 256) {
        int br = idx >> 9, hh = idx & 511, b = b0 + br;
        const float* p0 = prep0 + (size_t)b*NP;
        const float* p1 = prep1 + (size_t)b*NP;
        float iv = p0[hh]        + p1[hh]        + bias[hh];
        float jv = p0[512 + hh]  + p1[512 + hh]  + bias[512 + hh];
        float fv = p0[1024 + hh] + p1[1024 + hh] + bias[1024 + hh];
        float ov = p0[1536 + hh] + p1[1536 + hh] + bias[1536 + hh];
        float cold = cbuf[(size_t)b*HD + hh];
        float nc = tanhf(cold*sigm(fv + 1.0f) + sigm(iv)*tanhf(jv));
        cbuf[(size_t)b*HD + hh] = nc;
        smc[br*512 + hh] = nc;
        out[((size_t)t*BB + b)*640 + hh] = nc * sigm(ov);
      }
      for (int idx = tid; idx < 4*128; idx += 256) {
        int br = idx >> 7, rr = idx & 127, b = b0 + br;
        float om = prep0[(size_t)b*NP + 2048 + rr] + prep1[(size_t)b*NP + 2048 + rr] + bias[2048 + rr];
        out[((size_t)t*BB + b)*640 + 512 + rr] = hent[(size_t)b*RD + rr] * sigm(om);
      }
      __syncthreads();
      if (t < TT-1) {
        // wv = new_c @ trans_w^T + trans_b ;  score(t+1) += new_c @ fc_wc^T   (fp64)
        int o = tid & 127, mat = tid >> 7;
        const float* WT = mat ? fcwcT : transT;
        double a0=0., a1=0., a2=0., a3=0.;
        for (int k = 0; k < 512; k += 4) {
          float w0 = WT[(k+0)*128 + o], w1 = WT[(k+1)*128 + o];
          float w2 = WT[(k+2)*128 + o], w3 = WT[(k+3)*128 + o];
          float4 c0v = ld4(&smc[0*512 + k]);
          float4 c1v = ld4(&smc[1*512 + k]);
          float4 c2v = ld4(&smc[2*512 + k]);
          float4 c3v = ld4(&smc[3*512 + k]);
          a0 += (double)w0*c0v.x + (double)w1*c0v.y + (double)w2*c0v.z + (double)w3*c0v.w;
          a1 += (double)w0*c1v.x + (double)w1*c1v.y + (double)w2*c1v.z + (double)w3*c1v.w;
          a2 += (double)w0*c2v.x + (double)w1*c2v.y + (double)w2*c2v.z + (double)w3*c2v.w;
          a3 += (double)w0*c3v.x + (double)w1*c3v.y + (double)w2*c3v.z + (double)w3*c3v.w;
        }
        if (mat == 0) {
          smwv[0*128+o] = (float)(a0 + (double)trans_b[o]);
          smwv[1*128+o] = (float)(a1 + (double)trans_b[o]);
          smwv[2*128+o] = (float)(a2 + (double)trans_b[o]);
          smwv[3*128+o] = (float)(a3 + (double)trans_b[o]);
        } else {
          float* sx = out + ((size_t)(t+1)*BB)*640;
          sx[(size_t)(b0+0)*640 + 512 + o] = (float)((double)sx[(size_t)(b0+0)*640 + 512 + o] + a0);
          sx[(size_t)(b0+1)*640 + 512 + o] = (float)((double)sx[(size_t)(b0+1)*640 + 512 + o] + a1);
          sx[(size_t)(b0+2)*640 + 512 + o] = (float)((double)sx[(size_t)(b0+2)*640 + 512 + o] + a2);
          sx[(size_t)(b0+3)*640 + 512 + o] = (float)((double)sx[(size_t)(b0+3)*640 + 512 + o] + a3);
        }
        __syncthreads();
        for (int idx = tid; idx < 4*128; idx += 256) {
          int br = idx >> 7, rr = idx & 127, b = b0 + br;
          int slot = (t < MD) ? t : selb[b];
          hmem[((size_t)b*MD + slot)*RD + rr] = smwv[br*128 + rr];
        }
      }
    }
    if (!gbar()) return;
  }
}

extern "C" void kernel_launch(void* const* d_in, const int* in_sizes, int n_in,
                              void* d_out, int out_size, void* d_ws, size_t ws_size,
                              hipStream_t stream) {
  const float* x         = (const float*)d_in[0];
  const float* noise     = (const float*)d_in[1];
  const float* W_full    = (const float*)d_in[2];
  const float* bias      = (const float*)d_in[3];
  const float* W_full1   = (const float*)d_in[4];
  const float* bias1     = (const float*)d_in[5];
  const float* fc_w      = (const float*)d_in[6];
  const float* fc_b      = (const float*)d_in[7];
  const float* trans_w   = (const float*)d_in[8];
  const float* trans_b   = (const float*)d_in[9];
  const float* c_bias    = (const float*)d_in[10];
  const float* hmem_bias = (const float*)d_in[11];
  float* out = (float*)d_out;
  float* ws  = (float*)d_ws;

  k_pre  <<<dim3(256),  dim3(256), 0, stream>>>(fc_w, trans_w, c_bias, hmem_bias, ws);
  k_score<<<dim3(4096), dim3(256), 0, stream>>>(x, noise, fc_b, ws + OFF_FXT, out);
  k_scan <<<dim3(NBLK), dim3(256), 0, stream>>>(x, W_full, W_full1, bias, bias1,
                                                trans_b, out, ws);
}

// Round 3
// 43858.780 us; speedup vs baseline: 1.2775x; 1.2775x over previous
//
#include <hip/hip_runtime.h>
#include <cmath>

// MARNN scan v6 — persistent fused scan kernel with cache-silent barrier.
// v5 measured 56 ms (worse than v3's 38.2): VALUBusy 9%, FETCH 6.8 GB.
// Root cause: spin polls used ACQUIRE atomic loads — each emits buffer_inv
// (L1+L2 invalidate) on gfx950. 136 spinners invalidated every XCD's L2
// every ~30 cycles during barrier convergence, so computing blocks lost all
// weight locality (every Bs tile from HBM, ~900cyc, single-buffered).
// v6 barrier: per-block release flag (distinct lines, no RMW serialization),
// block-0 parallel aggregation, one release word, RELAXED polls, exactly ONE
// __threadfence per block per barrier at exit. Phase bodies verbatim v3.
//   P1 (blocks 0..79):  argmax + h_ent gather + gates1 GEMM (K-split x2)
//   P2 (blocks 0..135): pre GEMM with on-the-fly gating (K-split x2)
//   P3 (blocks 0..63):  epilogue (LSTM cell, outputs, fp64 GEMVs, hmem upd)

#define TT 256
#define BB 256
#define XD 256
#define HD 512
#define RD 128
#define MD 128
#define N1 640    // R + H      (gates1 width)
#define NP 2176   // R + 4H     (pre width)

// ---- ws layout (float offsets) — 5,964,288 floats, identical to v3 ----
#define OFF_C     0u         // cbuf  [B,H]
#define OFF_HMEM  131072u    // hmem  [B,M,R]
#define OFF_HENT  4325376u   // h_ent [B,R]
#define OFF_SEL   4358144u   // selbuf[B] int
#define OFF_FXT   4358400u   // fcxT  [256,128]  fc_w[:, :256]^T
#define OFF_TWT   4391168u   // transT[512,128]  trans_w^T
#define OFF_FWT   4456704u   // fcwcT [512,128]  fc_w[:,256:768]^T
#define OFF_HEAD0 4522240u   // head0 [M] double
#define OFF_G1P   4522496u   // g1 partials  float [2][B,N1]
#define OFF_PREP  4850176u   // pre partials float [2][B,NP]

#define NBLK 136

// barrier state in module globals — zero workspace growth
__device__ unsigned int g_flag[NBLK];
__device__ unsigned int g_rel;
__device__ unsigned int g_abrt;

__device__ __forceinline__ float sigm(float z){ return 1.0f/(1.0f + expf(-z)); }
__device__ __forceinline__ float4 ld4(const float* p){ return *(const float4*)p; }

// ---------- init: state, transposes, head0 (fp64), barrier reset ----------
__global__ __launch_bounds__(256)
void k_pre(const float* __restrict__ fc_w, const float* __restrict__ trans_w,
           const float* __restrict__ c_bias, const float* __restrict__ hmem_bias,
           float* __restrict__ ws)
{
  float*  cbuf   = ws + OFF_C;
  float*  hmem   = ws + OFF_HMEM;
  float*  fcxT   = ws + OFF_FXT;
  float*  transT = ws + OFF_TWT;
  float*  fcwcT  = ws + OFF_FWT;
  double* head0d = (double*)(ws + OFF_HEAD0);

  const int gt = blockIdx.x*256 + threadIdx.x, GT = gridDim.x*256;
  if (blockIdx.x == 0 && threadIdx.x < NBLK) g_flag[threadIdx.x] = 0u;
  if (gt == 0) { g_rel = 0u; g_abrt = 0u; }
  for (int i = gt; i < BB*HD;    i += GT) cbuf[i] = (float)tanh((double)c_bias[i & 511]);
  for (int i = gt; i < BB*MD*RD; i += GT) hmem[i] = hmem_bias[i & (MD*RD - 1)];
  for (int i = gt; i < XD*128;   i += GT) { int k=i>>7, m=i&127; fcxT[i]  = fc_w[(size_t)m*768 + k]; }
  for (int i = gt; i < HD*128;   i += GT) { int k=i>>7, o=i&127; transT[i] = trans_w[(size_t)o*512 + k];
                                            fcwcT[i]  = fc_w[(size_t)o*768 + 256 + k]; }
  if (blockIdx.x == 0 && threadIdx.x < 128) {
    double a = 0.0;
    for (int k = 0; k < 512; ++k)
      a += tanh((double)c_bias[k]) * (double)fc_w[(size_t)threadIdx.x*768 + 256 + k];
    head0d[threadIdx.x] = a;
  }
}

// ---------- score: out[t,b,512+m] = fp64(x-part head + fc_b + gumbel) ----------
__global__ __launch_bounds__(256)
void k_score(const float* __restrict__ x, const float* __restrict__ noise,
             const float* __restrict__ fc_b, const float* __restrict__ ws_fcxT,
             float* __restrict__ out)
{
  __shared__ float xs[16*256];
  const int tid = threadIdx.x;
  const int rbase = blockIdx.x * 16;           // 4096 blocks x 16 rows
  for (int i = tid; i < 16*64; i += 256) {
    int row = i >> 6, kq = (i & 63) << 2;
    *(float4*)&xs[row*256 + kq] = ld4(x + (size_t)(rbase + row)*XD + kq);
  }
  __syncthreads();
  const int m = tid & 127, r0 = (tid >> 7) * 8;
  double acc[8] = {};
  for (int k = 0; k < 256; ++k) {
    double wk = (double)ws_fcxT[k*128 + m];
    #pragma unroll
    for (int r = 0; r < 8; ++r) acc[r] += wk * (double)xs[(r0+r)*256 + k];
  }
  #pragma unroll
  for (int r = 0; r < 8; ++r) {
    size_t grow = (size_t)rbase + r0 + r;
    double g   = (double)noise[grow*MD + m];
    double gum = -log(1e-20 - log(1e-20 + g));
    out[grow*640 + 512 + m] = (float)(acc[r] + (double)fc_b[m] + gum);
  }
}

// ---------- persistent scan kernel ----------
__global__ __launch_bounds__(256)
void k_scan(const float* __restrict__ x, const float* __restrict__ W_full,
            const float* __restrict__ W_full1, const float* __restrict__ bias,
            const float* __restrict__ bias1, const float* __restrict__ trans_b,
            float* __restrict__ out, float* __restrict__ ws)
{
  __shared__ float As[16][68];
  __shared__ float Bs[16][128];     // P1 uses cols 0..63, P2 uses 0..127
  __shared__ int   sel[64];
  __shared__ float smc[4*512];
  __shared__ float smwv[4*128];
  __shared__ int   s_bad;

  const int tid = threadIdx.x, bid = blockIdx.x;
  unsigned int bars = 0;

  // cache-silent grid barrier:
  //   all blocks: release-store own flag (distinct lines, no RMW contention)
  //   block 0:    tid<NBLK poll flags RELAXED in parallel -> release g_rel
  //   others:     tid 0 polls g_rel RELAXED
  //   exactly one __threadfence (acquire) per block at exit
  auto gbar = [&]() -> bool {
    ++bars;
    if (tid == 0) s_bad = 0;
    __syncthreads();                                // phase done; s_bad init
    if (tid == 0)
      __hip_atomic_store(&g_flag[bid], bars, __ATOMIC_RELEASE, __HIP_MEMORY_SCOPE_AGENT);
    if (bid == 0) {
      if (tid < NBLK) {
        long long t0 = __builtin_amdgcn_s_memrealtime();
        while (__hip_atomic_load(&g_flag[tid], __ATOMIC_RELAXED, __HIP_MEMORY_SCOPE_AGENT) < bars) {
          __builtin_amdgcn_s_sleep(1);
          if (__hip_atomic_load(&g_abrt, __ATOMIC_RELAXED, __HIP_MEMORY_SCOPE_AGENT) != 0u ||
              __builtin_amdgcn_s_memrealtime() - t0 > 20000000LL) {   // fast-fail
            __hip_atomic_store(&g_abrt, 1u, __ATOMIC_RELAXED, __HIP_MEMORY_SCOPE_AGENT);
            s_bad = 1; break;
          }
        }
      }
      __syncthreads();                              // all flags observed (or bad)
      if (tid == 0) {
        if (s_bad == 0)
          __hip_atomic_store(&g_rel, bars, __ATOMIC_RELEASE, __HIP_MEMORY_SCOPE_AGENT);
        __threadfence();                            // single acquire for block 0
      }
      __syncthreads();
      return s_bad == 0;
    } else {
      if (tid == 0) {
        long long t0 = __builtin_amdgcn_s_memrealtime();
        while (__hip_atomic_load(&g_rel, __ATOMIC_RELAXED, __HIP_MEMORY_SCOPE_AGENT) < bars) {
          __builtin_amdgcn_s_sleep(1);
          if (__hip_atomic_load(&g_abrt, __ATOMIC_RELAXED, __HIP_MEMORY_SCOPE_AGENT) != 0u ||
              __builtin_amdgcn_s_memrealtime() - t0 > 25000000LL) {
            __hip_atomic_store(&g_abrt, 1u, __ATOMIC_RELAXED, __HIP_MEMORY_SCOPE_AGENT);
            s_bad = 1; break;
          }
        }
        __threadfence();                            // single acquire per barrier
      }
      __syncthreads();
      return s_bad == 0;
    }
  };

  for (int t = 0; t < TT; ++t) {
    // ================= P1: argmax + gather + gates1 GEMM (blocks 0..79) =================
    if (bid < 80) {
      const int rt = bid & 3, ct = (bid >> 2) % 10, kc = bid / 40;
      const int r0 = rt*64, n0 = ct*64, kbeg = kc*448;
      const float* cbuf = ws + OFF_C;
      const float* hmem = ws + OFF_HMEM;
      float*  hent  = ws + OFF_HENT;
      int*    selb  = (int*)(ws + OFF_SEL);
      double* head0d= (double*)(ws + OFF_HEAD0);
      float*  g1p   = ws + OFF_G1P + (size_t)kc*BB*N1;

      if (kc == 1) {                               // this K-range touches h_entry
        if (tid < 64) {
          const float* sc = out + ((size_t)t*BB + r0 + tid)*640 + 512;
          int bi = 0;
          if (t == 0) { double best = -1e300;
            for (int m = 0; m < 128; ++m) { double v = (double)sc[m] + head0d[m]; if (v > best) { best = v; bi = m; } } }
          else { float best = -3.4e38f;
            for (int m = 0; m < 128; ++m) { float v = sc[m]; if (v > best) { best = v; bi = m; } } }
          sel[tid] = bi;
        }
        __syncthreads();
        if (ct == 0) {                             // designated writer per row-group
          if (tid < 64) selb[r0 + tid] = sel[tid];
          for (int idx = tid; idx < 64*128; idx += 256) {
            int row = idx >> 7, rr = idx & 127;
            hent[(size_t)(r0+row)*RD + rr] = hmem[((size_t)(r0+row)*MD + sel[row])*RD + rr];
          }
        }
      }

      float  acc[4][4] = {};
      double accd[4][4] = {};
      const int tx = tid & 15, ty = tid >> 4;
      const int arow = tid >> 2, akq = (tid & 3) << 2;
      const int bkk = tid >> 4, bnq = (tid & 15) << 2;

      for (int k0 = kbeg; k0 < kbeg + 448; k0 += 16) {
        __syncthreads();
        { // stage A (k-major transpose)
          int b = r0 + arow, k = k0 + akq;
          float4 v;
          if (k < XD)           v = ld4(x + ((size_t)t*BB + b)*XD + k);
          else if (k < XD + HD) v = ld4(cbuf + (size_t)b*HD + (k - XD));
          else                  v = ld4(hmem + ((size_t)b*MD + sel[arow])*RD + (k - (XD+HD)));
          As[akq+0][arow] = v.x; As[akq+1][arow] = v.y;
          As[akq+2][arow] = v.z; As[akq+3][arow] = v.w;
        }
        *(float4*)&Bs[bkk][bnq] = ld4(W_full1 + (size_t)(k0 + bkk)*N1 + n0 + bnq);
        __syncthreads();
        #pragma unroll
        for (int kk = 0; kk < 16; ++kk) {
          float a[4], b[4];
          *(float4*)a = ld4(&As[kk][ty*4]);
          *(float4*)b = ld4(&Bs[kk][tx*4]);
          #pragma unroll
          for (int i = 0; i < 4; ++i)
            #pragma unroll
            for (int j = 0; j < 4; ++j)
              acc[i][j] = fmaf(a[i], b[j], acc[i][j]);
          if ((kk & 7) == 7) {                     // fp64 fold every 8 k
            #pragma unroll
            for (int i = 0; i < 4; ++i)
              #pragma unroll
              for (int j = 0; j < 4; ++j) { accd[i][j] += (double)acc[i][j]; acc[i][j] = 0.f; }
          }
        }
      }
      #pragma unroll
      for (int i = 0; i < 4; ++i)
        #pragma unroll
        for (int j = 0; j < 4; ++j)
          g1p[(size_t)(r0 + ty*4 + i)*N1 + n0 + tx*4 + j] = (float)accd[i][j];
    }
    if (!gbar()) return;

    // ================= P2: pre GEMM with on-the-fly gating (all 136 blocks) =================
    {
      const int rt = bid & 3, ct = (bid >> 2) % 17, kc = bid / 68;
      const int r0 = rt*64, n0 = ct*128, kbeg = kc*448;
      const float* cbuf = ws + OFF_C;
      const float* hent = ws + OFF_HENT;
      const float* g1p0 = ws + OFF_G1P;
      const float* g1p1 = g1p0 + (size_t)BB*N1;
      float* prep = ws + OFF_PREP + (size_t)kc*BB*NP;

      float  acc[4][8] = {};
      double accd[4][8] = {};
      const int tx = tid & 15, ty = tid >> 4;
      const int arow = tid >> 2, akq = (tid & 3) << 2;

      for (int k0 = kbeg; k0 < kbeg + 448; k0 += 16) {
        __syncthreads();
        { // stage A with gating applied at load time
          int b = r0 + arow, k = k0 + akq;
          float4 v;
          if (k < XD) v = ld4(x + ((size_t)t*BB + b)*XD + k);
          else if (k < XD + HD) {
            int j = k - XD;
            v = ld4(cbuf + (size_t)b*HD + j);
            float4 p0 = ld4(g1p0 + (size_t)b*N1 + j);
            float4 p1 = ld4(g1p1 + (size_t)b*N1 + j);
            float4 bb = ld4(bias1 + j);
            v.x *= sigm(p0.x + p1.x + bb.x);
            v.y *= sigm(p0.y + p1.y + bb.y);
            v.z *= sigm(p0.z + p1.z + bb.z);
            v.w *= sigm(p0.w + p1.w + bb.w);
          } else {
            int j = k - (XD + HD);
            v = ld4(hent + (size_t)b*RD + j);
            float4 p0 = ld4(g1p0 + (size_t)b*N1 + 512 + j);
            float4 p1 = ld4(g1p1 + (size_t)b*N1 + 512 + j);
            float4 bb = ld4(bias1 + 512 + j);
            v.x *= sigm(p0.x + p1.x + bb.x);
            v.y *= sigm(p0.y + p1.y + bb.y);
            v.z *= sigm(p0.z + p1.z + bb.z);
            v.w *= sigm(p0.w + p1.w + bb.w);
          }
          As[akq+0][arow] = v.x; As[akq+1][arow] = v.y;
          As[akq+2][arow] = v.z; As[akq+3][arow] = v.w;
        }
        #pragma unroll
        for (int rep = 0; rep < 2; ++rep) {
          int idx = tid + rep*256, kk = idx >> 5, nq = (idx & 31) << 2;
          *(float4*)&Bs[kk][nq] = ld4(W_full + (size_t)(k0 + kk)*NP + n0 + nq);
        }
        __syncthreads();
        #pragma unroll
        for (int kk = 0; kk < 16; ++kk) {
          float a[4], b[8];
          *(float4*)a = ld4(&As[kk][ty*4]);
          *(float4*)&b[0] = ld4(&Bs[kk][tx*8]);
          *(float4*)&b[4] = ld4(&Bs[kk][tx*8 + 4]);
          #pragma unroll
          for (int i = 0; i < 4; ++i)
            #pragma unroll
            for (int j = 0; j < 8; ++j)
              acc[i][j] = fmaf(a[i], b[j], acc[i][j]);
          if ((kk & 7) == 7) {
            #pragma unroll
            for (int i = 0; i < 4; ++i)
              #pragma unroll
              for (int j = 0; j < 8; ++j) { accd[i][j] += (double)acc[i][j]; acc[i][j] = 0.f; }
          }
        }
      }
      #pragma unroll
      for (int i = 0; i < 4; ++i)
        #pragma unroll
        for (int j = 0; j < 8; ++j)
          prep[(size_t)(r0 + ty*4 + i)*NP + n0 + tx*8 + j] = (float)accd[i][j];
    }
    if (!gbar()) return;

    // ================= P3: epilogue (blocks 0..63, 4 batch rows each) =================
    if (bid < 64) {
      const int b0 = bid*4;
      float*  cbuf   = ws + OFF_C;
      float*  hmem   = ws + OFF_HMEM;
      float*  hent   = ws + OFF_HENT;
      int*    selb   = (int*)(ws + OFF_SEL);
      float*  transT = ws + OFF_TWT;
      float*  fcwcT  = ws + OFF_FWT;
      const float* prep0 = ws + OFF_PREP;
      const float* prep1 = prep0 + (size_t)BB*NP;

      for (int idx = tid; idx < 4*512; idx += 256) {
        int br = idx >> 9, hh = idx & 511, b = b0 + br;
        const float* p0 = prep0 + (size_t)b*NP;
        const float* p1 = prep1 + (size_t)b*NP;
        float iv = p0[hh]        + p1[hh]        + bias[hh];
        float jv = p0[512 + hh]  + p1[512 + hh]  + bias[512 + hh];
        float fv = p0[1024 + hh] + p1[1024 + hh] + bias[1024 + hh];
        float ov = p0[1536 + hh] + p1[1536 + hh] + bias[1536 + hh];
        float cold = cbuf[(size_t)b*HD + hh];
        float nc = tanhf(cold*sigm(fv + 1.0f) + sigm(iv)*tanhf(jv));
        cbuf[(size_t)b*HD + hh] = nc;
        smc[br*512 + hh] = nc;
        out[((size_t)t*BB + b)*640 + hh] = nc * sigm(ov);
      }
      for (int idx = tid; idx < 4*128; idx += 256) {
        int br = idx >> 7, rr = idx & 127, b = b0 + br;
        float om = prep0[(size_t)b*NP + 2048 + rr] + prep1[(size_t)b*NP + 2048 + rr] + bias[2048 + rr];
        out[((size_t)t*BB + b)*640 + 512 + rr] = hent[(size_t)b*RD + rr] * sigm(om);
      }
      __syncthreads();
      if (t < TT-1) {
        // wv = new_c @ trans_w^T + trans_b ;  score(t+1) += new_c @ fc_wc^T   (fp64)
        int o = tid & 127, mat = tid >> 7;
        const float* WT = mat ? fcwcT : transT;
        double a0=0., a1=0., a2=0., a3=0.;
        for (int k = 0; k < 512; k += 4) {
          float w0 = WT[(k+0)*128 + o], w1 = WT[(k+1)*128 + o];
          float w2 = WT[(k+2)*128 + o], w3 = WT[(k+3)*128 + o];
          float4 c0v = ld4(&smc[0*512 + k]);
          float4 c1v = ld4(&smc[1*512 + k]);
          float4 c2v = ld4(&smc[2*512 + k]);
          float4 c3v = ld4(&smc[3*512 + k]);
          a0 += (double)w0*c0v.x + (double)w1*c0v.y + (double)w2*c0v.z + (double)w3*c0v.w;
          a1 += (double)w0*c1v.x + (double)w1*c1v.y + (double)w2*c1v.z + (double)w3*c1v.w;
          a2 += (double)w0*c2v.x + (double)w1*c2v.y + (double)w2*c2v.z + (double)w3*c2v.w;
          a3 += (double)w0*c3v.x + (double)w1*c3v.y + (double)w2*c3v.z + (double)w3*c3v.w;
        }
        if (mat == 0) {
          smwv[0*128+o] = (float)(a0 + (double)trans_b[o]);
          smwv[1*128+o] = (float)(a1 + (double)trans_b[o]);
          smwv[2*128+o] = (float)(a2 + (double)trans_b[o]);
          smwv[3*128+o] = (float)(a3 + (double)trans_b[o]);
        } else {
          float* sx = out + ((size_t)(t+1)*BB)*640;
          sx[(size_t)(b0+0)*640 + 512 + o] = (float)((double)sx[(size_t)(b0+0)*640 + 512 + o] + a0);
          sx[(size_t)(b0+1)*640 + 512 + o] = (float)((double)sx[(size_t)(b0+1)*640 + 512 + o] + a1);
          sx[(size_t)(b0+2)*640 + 512 + o] = (float)((double)sx[(size_t)(b0+2)*640 + 512 + o] + a2);
          sx[(size_t)(b0+3)*640 + 512 + o] = (float)((double)sx[(size_t)(b0+3)*640 + 512 + o] + a3);
        }
        __syncthreads();
        for (int idx = tid; idx < 4*128; idx += 256) {
          int br = idx >> 7, rr = idx & 127, b = b0 + br;
          int slot = (t < MD) ? t : selb[b];
          hmem[((size_t)b*MD + slot)*RD + rr] = smwv[br*128 + rr];
        }
      }
    }
    if (!gbar()) return;
  }
}

extern "C" void kernel_launch(void* const* d_in, const int* in_sizes, int n_in,
                              void* d_out, int out_size, void* d_ws, size_t ws_size,
                              hipStream_t stream) {
  const float* x         = (const float*)d_in[0];
  const float* noise     = (const float*)d_in[1];
  const float* W_full    = (const float*)d_in[2];
  const float* bias      = (const float*)d_in[3];
  const float* W_full1   = (const float*)d_in[4];
  const float* bias1     = (const float*)d_in[5];
  const float* fc_w      = (const float*)d_in[6];
  const float* fc_b      = (const float*)d_in[7];
  const float* trans_w   = (const float*)d_in[8];
  const float* trans_b   = (const float*)d_in[9];
  const float* c_bias    = (const float*)d_in[10];
  const float* hmem_bias = (const float*)d_in[11];
  float* out = (float*)d_out;
  float* ws  = (float*)d_ws;

  k_pre  <<<dim3(256),  dim3(256), 0, stream>>>(fc_w, trans_w, c_bias, hmem_bias, ws);
  k_score<<<dim3(4096), dim3(256), 0, stream>>>(x, noise, fc_b, ws + OFF_FXT, out);
  k_scan <<<dim3(NBLK), dim3(256), 0, stream>>>(x, W_full, W_full1, bias, bias1,
                                                trans_b, out, ws);
}

// Round 4
// 40922.327 us; speedup vs baseline: 1.3692x; 1.0718x over previous
//
#include <hip/hip_runtime.h>
#include <cmath>

// MARNN scan v7 — persistent fused scan, latency-attacked.
// v6 measured 43.3 ms: VALUBusy 12%, Occupancy 6.6% (136 blocks = 120 idle
// CUs, 1 wave/SIMD), FETCH 6.8 GB identical to v5 (refetch is rt-sibling
// panel streaming across ~4 XCDs, not barrier invalidation). v7 keeps the
// v6 barrier and applies three BIT-IDENTICAL structural changes:
//  1) row-split x2: P1 rt=8 (160 blk, 32-row tiles), P2 rt=8 (272 blk),
//     P3 128 blk x 2 rows. NBLK=320, all resident (26KB LDS, ~150 VGPR).
//  2) reg-staged double-buffer (issue loads -> compute -> ds_write -> 1 sync)
//     so global latency hides under the fma loop.
//  3) exact XCD grouping: bid=(x8=bid&7, s8=bid>>3), combo c = x8+8*(s8>>3),
//     rt = s8&7 -> all 8 rt-siblings of a weight panel share bid%8 (same XCD)
//     -> each panel streamed once per XCD L2.
// Per-element fma order, 8-k fp32->fp64 folds, kc=2 k-split, fp64 GEMV
// expressions are UNTOUCHED -> arithmetic bit-identical to v3/v6.

#define TT 256
#define BB 256
#define XD 256
#define HD 512
#define RD 128
#define MD 128
#define N1 640    // R + H      (gates1 width)
#define NP 2176   // R + 4H     (pre width)

// ---- ws layout (float offsets) — 5,964,288 floats, identical to v3 ----
#define OFF_C     0u
#define OFF_HMEM  131072u
#define OFF_HENT  4325376u
#define OFF_SEL   4358144u
#define OFF_FXT   4358400u
#define OFF_TWT   4391168u
#define OFF_FWT   4456704u
#define OFF_HEAD0 4522240u
#define OFF_G1P   4522496u
#define OFF_PREP  4850176u

#define NBLK 320

// barrier state in module globals — zero workspace growth; 64B-padded flags
__device__ unsigned int g_flag[NBLK * 16];
__device__ unsigned int g_rel;
__device__ unsigned int g_abrt;

__device__ __forceinline__ float sigm(float z){ return 1.0f/(1.0f + expf(-z)); }
__device__ __forceinline__ float4 ld4(const float* p){ return *(const float4*)p; }

// ---------- init ----------
__global__ __launch_bounds__(256)
void k_pre(const float* __restrict__ fc_w, const float* __restrict__ trans_w,
           const float* __restrict__ c_bias, const float* __restrict__ hmem_bias,
           float* __restrict__ ws)
{
  float*  cbuf   = ws + OFF_C;
  float*  hmem   = ws + OFF_HMEM;
  float*  fcxT   = ws + OFF_FXT;
  float*  transT = ws + OFF_TWT;
  float*  fcwcT  = ws + OFF_FWT;
  double* head0d = (double*)(ws + OFF_HEAD0);

  const int gt = blockIdx.x*256 + threadIdx.x, GT = gridDim.x*256;
  for (int i = gt; i < NBLK*16; i += GT) g_flag[i] = 0u;
  if (gt == 0) { g_rel = 0u; g_abrt = 0u; }
  for (int i = gt; i < BB*HD;    i += GT) cbuf[i] = (float)tanh((double)c_bias[i & 511]);
  for (int i = gt; i < BB*MD*RD; i += GT) hmem[i] = hmem_bias[i & (MD*RD - 1)];
  for (int i = gt; i < XD*128;   i += GT) { int k=i>>7, m=i&127; fcxT[i]  = fc_w[(size_t)m*768 + k]; }
  for (int i = gt; i < HD*128;   i += GT) { int k=i>>7, o=i&127; transT[i] = trans_w[(size_t)o*512 + k];
                                            fcwcT[i]  = fc_w[(size_t)o*768 + 256 + k]; }
  if (blockIdx.x == 0 && threadIdx.x < 128) {
    double a = 0.0;
    for (int k = 0; k < 512; ++k)
      a += tanh((double)c_bias[k]) * (double)fc_w[(size_t)threadIdx.x*768 + 256 + k];
    head0d[threadIdx.x] = a;
  }
}

// ---------- score (unchanged) ----------
__global__ __launch_bounds__(256)
void k_score(const float* __restrict__ x, const float* __restrict__ noise,
             const float* __restrict__ fc_b, const float* __restrict__ ws_fcxT,
             float* __restrict__ out)
{
  __shared__ float xs[16*256];
  const int tid = threadIdx.x;
  const int rbase = blockIdx.x * 16;
  for (int i = tid; i < 16*64; i += 256) {
    int row = i >> 6, kq = (i & 63) << 2;
    *(float4*)&xs[row*256 + kq] = ld4(x + (size_t)(rbase + row)*XD + kq);
  }
  __syncthreads();
  const int m = tid & 127, r0 = (tid >> 7) * 8;
  double acc[8] = {};
  for (int k = 0; k < 256; ++k) {
    double wk = (double)ws_fcxT[k*128 + m];
    #pragma unroll
    for (int r = 0; r < 8; ++r) acc[r] += wk * (double)xs[(r0+r)*256 + k];
  }
  #pragma unroll
  for (int r = 0; r < 8; ++r) {
    size_t grow = (size_t)rbase + r0 + r;
    double g   = (double)noise[grow*MD + m];
    double gum = -log(1e-20 - log(1e-20 + g));
    out[grow*640 + 512 + m] = (float)(acc[r] + (double)fc_b[m] + gum);
  }
}

// ---------- persistent scan kernel ----------
__global__ __launch_bounds__(256, 2)
void k_scan(const float* __restrict__ x, const float* __restrict__ W_full,
            const float* __restrict__ W_full1, const float* __restrict__ bias,
            const float* __restrict__ bias1, const float* __restrict__ trans_b,
            float* __restrict__ out, float* __restrict__ ws)
{
  __shared__ float As[2][16][36];     // 32 rows + pad
  __shared__ float Bs[2][16][128];    // P1 uses cols 0..63
  __shared__ int   sel[32];
  __shared__ float smc[2*512];
  __shared__ float smwv[2*128];
  __shared__ int   s_bad;

  const int tid = threadIdx.x, bid = blockIdx.x;
  const int x8 = bid & 7, s8 = bid >> 3;        // xcd class, slot
  unsigned int bars = 0;

  // cache-silent grid barrier (v6, proven): per-block release flag,
  // block-0 parallel aggregation, one release word, RELAXED polls,
  // one __threadfence per block per barrier.
  auto gbar = [&]() -> bool {
    ++bars;
    if (tid == 0) s_bad = 0;
    __syncthreads();
    if (tid == 0)
      __hip_atomic_store(&g_flag[bid*16], bars, __ATOMIC_RELEASE, __HIP_MEMORY_SCOPE_AGENT);
    if (bid == 0) {
      for (int f = tid; f < NBLK; f += 256) {
        long long t0 = __builtin_amdgcn_s_memrealtime();
        while (__hip_atomic_load(&g_flag[f*16], __ATOMIC_RELAXED, __HIP_MEMORY_SCOPE_AGENT) < bars) {
          __builtin_amdgcn_s_sleep(1);
          if (__hip_atomic_load(&g_abrt, __ATOMIC_RELAXED, __HIP_MEMORY_SCOPE_AGENT) != 0u ||
              __builtin_amdgcn_s_memrealtime() - t0 > 20000000LL) {
            __hip_atomic_store(&g_abrt, 1u, __ATOMIC_RELAXED, __HIP_MEMORY_SCOPE_AGENT);
            s_bad = 1; break;
          }
        }
        if (s_bad) break;
      }
      __syncthreads();
      if (tid == 0) {
        if (s_bad == 0)
          __hip_atomic_store(&g_rel, bars, __ATOMIC_RELEASE, __HIP_MEMORY_SCOPE_AGENT);
        __threadfence();
      }
      __syncthreads();
      return s_bad == 0;
    } else {
      if (tid == 0) {
        long long t0 = __builtin_amdgcn_s_memrealtime();
        while (__hip_atomic_load(&g_rel, __ATOMIC_RELAXED, __HIP_MEMORY_SCOPE_AGENT) < bars) {
          __builtin_amdgcn_s_sleep(1);
          if (__hip_atomic_load(&g_abrt, __ATOMIC_RELAXED, __HIP_MEMORY_SCOPE_AGENT) != 0u ||
              __builtin_amdgcn_s_memrealtime() - t0 > 25000000LL) {
            __hip_atomic_store(&g_abrt, 1u, __ATOMIC_RELAXED, __HIP_MEMORY_SCOPE_AGENT);
            s_bad = 1; break;
          }
        }
        __threadfence();
      }
      __syncthreads();
      return s_bad == 0;
    }
  };

  // phase-role decode (rt-siblings of one weight panel share bid%8 -> one XCD)
  const int m8 = s8 >> 3;                 // 0..4
  const int rt = s8 & 7;                  // 0..7
  const int c1 = x8 + (m8 << 3);          // P1 combo (valid if s8<24 && c1<20)
  const bool p1_act = (s8 < 24) && (c1 < 20);
  const int ct1 = c1 % 10, kc1 = c1 / 10;
  const int c2 = x8 + (m8 << 3);          // P2 combo (valid if c2<34)
  const bool p2_act = (c2 < 34);
  const int ct2 = c2 % 17, kc2 = c2 / 17;

  float* cbuf = ws + OFF_C;
  float* hmem = ws + OFF_HMEM;
  float* hent = ws + OFF_HENT;
  int*   selb = (int*)(ws + OFF_SEL);
  double* head0d = (double*)(ws + OFF_HEAD0);

  for (int t = 0; t < TT; ++t) {
    // ======== P1: argmax + gather + gates1 GEMM (tiles 32x64, dbuf) ========
    if (p1_act) {
      const int r0 = rt*32, n0 = ct1*64, kbeg = kc1*448;
      float* g1p = ws + OFF_G1P + (size_t)kc1*BB*N1;

      if (kc1 == 1) {
        if (tid < 32) {
          const float* sc = out + ((size_t)t*BB + r0 + tid)*640 + 512;
          int bi = 0;
          if (t == 0) { double best = -1e300;
            for (int m = 0; m < 128; ++m) { double v = (double)sc[m] + head0d[m]; if (v > best) { best = v; bi = m; } } }
          else { float best = -3.4e38f;
            for (int m = 0; m < 128; ++m) { float v = sc[m]; if (v > best) { best = v; bi = m; } } }
          sel[tid] = bi;
        }
        __syncthreads();
        if (ct1 == 0) {
          if (tid < 32) selb[r0 + tid] = sel[tid];
          for (int idx = tid; idx < 32*128; idx += 256) {
            int row = idx >> 7, rr = idx & 127;
            hent[(size_t)(r0+row)*RD + rr] = hmem[((size_t)(r0+row)*MD + sel[row])*RD + rr];
          }
        }
      }

      const int tx = tid & 15, ty = tid >> 4;
      const int ar = tid >> 2, aq = (tid & 3) << 2;      // A stage: tid<128
      const int bkk = tid >> 4, bnq = (tid & 15) << 2;   // B stage: 1 f4/thread

      float4 va, vb;
      auto issue1 = [&](int k0) {
        if (tid < 128) {
          int b = r0 + ar, k = k0 + aq;
          if (k < XD)           va = ld4(x + ((size_t)t*BB + b)*XD + k);
          else if (k < XD + HD) va = ld4(cbuf + (size_t)b*HD + (k - XD));
          else                  va = ld4(hmem + ((size_t)b*MD + sel[ar])*RD + (k - (XD+HD)));
        }
        vb = ld4(W_full1 + (size_t)(k0 + bkk)*N1 + n0 + bnq);
      };
      auto write1 = [&](int buf) {
        if (tid < 128) {
          As[buf][aq+0][ar] = va.x; As[buf][aq+1][ar] = va.y;
          As[buf][aq+2][ar] = va.z; As[buf][aq+3][ar] = va.w;
        }
        *(float4*)&Bs[buf][bkk][bnq] = vb;
      };

      float  acc[2][4] = {};
      double accd[2][4] = {};
      int cur = 0;
      issue1(kbeg); write1(0);
      __syncthreads();
      for (int it = 0; it < 28; ++it) {
        const bool pf = (it + 1 < 28);
        if (pf) issue1(kbeg + (it+1)*16);
        #pragma unroll
        for (int kk = 0; kk < 16; ++kk) {
          float a[2], b[4];
          *(float2*)a = *(const float2*)&As[cur][kk][ty*2];
          *(float4*)b = ld4(&Bs[cur][kk][tx*4]);
          #pragma unroll
          for (int i = 0; i < 2; ++i)
            #pragma unroll
            for (int j = 0; j < 4; ++j)
              acc[i][j] = fmaf(a[i], b[j], acc[i][j]);
          if ((kk & 7) == 7) {
            #pragma unroll
            for (int i = 0; i < 2; ++i)
              #pragma unroll
              for (int j = 0; j < 4; ++j) { accd[i][j] += (double)acc[i][j]; acc[i][j] = 0.f; }
          }
        }
        if (pf) write1(cur ^ 1);
        __syncthreads();
        cur ^= 1;
      }
      #pragma unroll
      for (int i = 0; i < 2; ++i)
        #pragma unroll
        for (int j = 0; j < 4; ++j)
          g1p[(size_t)(r0 + ty*2 + i)*N1 + n0 + tx*4 + j] = (float)accd[i][j];
    }
    if (!gbar()) return;

    // ======== P2: pre GEMM with on-the-fly gating (tiles 32x128, dbuf) ========
    if (p2_act) {
      const int r0 = rt*32, n0 = ct2*128, kbeg = kc2*448;
      const float* g1p0 = ws + OFF_G1P;
      const float* g1p1 = g1p0 + (size_t)BB*N1;
      float* prep = ws + OFF_PREP + (size_t)kc2*BB*NP;

      const int tx = tid & 15, ty = tid >> 4;
      const int ar = tid >> 2, aq = (tid & 3) << 2;      // A stage: tid<128

      float4 va, p0v, p1v, bbv, vb0, vb1;
      int areg = 0;
      auto issue2 = [&](int k0) {
        if (tid < 128) {
          int b = r0 + ar, k = k0 + aq;
          if (k < XD) { areg = 0; va = ld4(x + ((size_t)t*BB + b)*XD + k); }
          else if (k < XD + HD) {
            int j = k - XD; areg = 1;
            va  = ld4(cbuf + (size_t)b*HD + j);
            p0v = ld4(g1p0 + (size_t)b*N1 + j);
            p1v = ld4(g1p1 + (size_t)b*N1 + j);
            bbv = ld4(bias1 + j);
          } else {
            int j = k - (XD + HD); areg = 1;
            va  = ld4(hent + (size_t)b*RD + j);
            p0v = ld4(g1p0 + (size_t)b*N1 + 512 + j);
            p1v = ld4(g1p1 + (size_t)b*N1 + 512 + j);
            bbv = ld4(bias1 + 512 + j);
          }
        }
        vb0 = ld4(W_full + (size_t)(k0 + (tid>>5))*NP + n0 + ((tid&31)<<2));
        vb1 = ld4(W_full + (size_t)(k0 + (tid>>5) + 8)*NP + n0 + ((tid&31)<<2));
      };
      auto write2 = [&](int buf) {
        if (tid < 128) {
          float4 v = va;
          if (areg) {
            v.x *= sigm(p0v.x + p1v.x + bbv.x);
            v.y *= sigm(p0v.y + p1v.y + bbv.y);
            v.z *= sigm(p0v.z + p1v.z + bbv.z);
            v.w *= sigm(p0v.w + p1v.w + bbv.w);
          }
          As[buf][aq+0][ar] = v.x; As[buf][aq+1][ar] = v.y;
          As[buf][aq+2][ar] = v.z; As[buf][aq+3][ar] = v.w;
        }
        *(float4*)&Bs[buf][tid>>5][(tid&31)<<2] = vb0;
        *(float4*)&Bs[buf][(tid>>5) + 8][(tid&31)<<2] = vb1;
      };

      float  acc[2][8] = {};
      double accd[2][8] = {};
      int cur = 0;
      issue2(kbeg); write2(0);
      __syncthreads();
      for (int it = 0; it < 28; ++it) {
        const bool pf = (it + 1 < 28);
        if (pf) issue2(kbeg + (it+1)*16);
        #pragma unroll
        for (int kk = 0; kk < 16; ++kk) {
          float a[2], b[8];
          *(float2*)a = *(const float2*)&As[cur][kk][ty*2];
          *(float4*)&b[0] = ld4(&Bs[cur][kk][tx*8]);
          *(float4*)&b[4] = ld4(&Bs[cur][kk][tx*8 + 4]);
          #pragma unroll
          for (int i = 0; i < 2; ++i)
            #pragma unroll
            for (int j = 0; j < 8; ++j)
              acc[i][j] = fmaf(a[i], b[j], acc[i][j]);
          if ((kk & 7) == 7) {
            #pragma unroll
            for (int i = 0; i < 2; ++i)
              #pragma unroll
              for (int j = 0; j < 8; ++j) { accd[i][j] += (double)acc[i][j]; acc[i][j] = 0.f; }
          }
        }
        if (pf) write2(cur ^ 1);
        __syncthreads();
        cur ^= 1;
      }
      #pragma unroll
      for (int i = 0; i < 2; ++i)
        #pragma unroll
        for (int j = 0; j < 8; ++j)
          prep[(size_t)(r0 + ty*2 + i)*NP + n0 + tx*8 + j] = (float)accd[i][j];
    }
    if (!gbar()) return;

    // ======== P3: epilogue (128 blocks x 2 batch rows) ========
    if (bid < 128) {
      const int b0 = bid*2;
      float*  transT = ws + OFF_TWT;
      float*  fcwcT  = ws + OFF_FWT;
      const float* prep0 = ws + OFF_PREP;
      const float* prep1 = prep0 + (size_t)BB*NP;

      for (int idx = tid; idx < 2*512; idx += 256) {
        int br = idx >> 9, hh = idx & 511, b = b0 + br;
        const float* p0 = prep0 + (size_t)b*NP;
        const float* p1 = prep1 + (size_t)b*NP;
        float iv = p0[hh]        + p1[hh]        + bias[hh];
        float jv = p0[512 + hh]  + p1[512 + hh]  + bias[512 + hh];
        float fv = p0[1024 + hh] + p1[1024 + hh] + bias[1024 + hh];
        float ov = p0[1536 + hh] + p1[1536 + hh] + bias[1536 + hh];
        float cold = cbuf[(size_t)b*HD + hh];
        float nc = tanhf(cold*sigm(fv + 1.0f) + sigm(iv)*tanhf(jv));
        cbuf[(size_t)b*HD + hh] = nc;
        smc[br*512 + hh] = nc;
        out[((size_t)t*BB + b)*640 + hh] = nc * sigm(ov);
      }
      for (int idx = tid; idx < 2*128; idx += 256) {
        int br = idx >> 7, rr = idx & 127, b = b0 + br;
        float om = prep0[(size_t)b*NP + 2048 + rr] + prep1[(size_t)b*NP + 2048 + rr] + bias[2048 + rr];
        out[((size_t)t*BB + b)*640 + 512 + rr] = hent[(size_t)b*RD + rr] * sigm(om);
      }
      __syncthreads();
      if (t < TT-1) {
        int o = tid & 127, mat = tid >> 7;
        const float* WT = mat ? fcwcT : transT;
        double a0=0., a1=0.;
        for (int k = 0; k < 512; k += 4) {
          float w0 = WT[(k+0)*128 + o], w1 = WT[(k+1)*128 + o];
          float w2 = WT[(k+2)*128 + o], w3 = WT[(k+3)*128 + o];
          float4 c0v = ld4(&smc[0*512 + k]);
          float4 c1v = ld4(&smc[1*512 + k]);
          a0 += (double)w0*c0v.x + (double)w1*c0v.y + (double)w2*c0v.z + (double)w3*c0v.w;
          a1 += (double)w0*c1v.x + (double)w1*c1v.y + (double)w2*c1v.z + (double)w3*c1v.w;
        }
        if (mat == 0) {
          smwv[0*128+o] = (float)(a0 + (double)trans_b[o]);
          smwv[1*128+o] = (float)(a1 + (double)trans_b[o]);
        } else {
          float* sx = out + ((size_t)(t+1)*BB)*640;
          sx[(size_t)(b0+0)*640 + 512 + o] = (float)((double)sx[(size_t)(b0+0)*640 + 512 + o] + a0);
          sx[(size_t)(b0+1)*640 + 512 + o] = (float)((double)sx[(size_t)(b0+1)*640 + 512 + o] + a1);
        }
        __syncthreads();
        for (int idx = tid; idx < 2*128; idx += 256) {
          int br = idx >> 7, rr = idx & 127, b = b0 + br;
          int slot = (t < MD) ? t : selb[b];
          hmem[((size_t)b*MD + slot)*RD + rr] = smwv[br*128 + rr];
        }
      }
    }
    if (!gbar()) return;
  }
}

extern "C" void kernel_launch(void* const* d_in, const int* in_sizes, int n_in,
                              void* d_out, int out_size, void* d_ws, size_t ws_size,
                              hipStream_t stream) {
  const float* x         = (const float*)d_in[0];
  const float* noise     = (const float*)d_in[1];
  const float* W_full    = (const float*)d_in[2];
  const float* bias      = (const float*)d_in[3];
  const float* W_full1   = (const float*)d_in[4];
  const float* bias1     = (const float*)d_in[5];
  const float* fc_w      = (const float*)d_in[6];
  const float* fc_b      = (const float*)d_in[7];
  const float* trans_w   = (const float*)d_in[8];
  const float* trans_b   = (const float*)d_in[9];
  const float* c_bias    = (const float*)d_in[10];
  const float* hmem_bias = (const float*)d_in[11];
  float* out = (float*)d_out;
  float* ws  = (float*)d_ws;

  k_pre  <<<dim3(256),  dim3(256), 0, stream>>>(fc_w, trans_w, c_bias, hmem_bias, ws);
  k_score<<<dim3(4096), dim3(256), 0, stream>>>(x, noise, fc_b, ws + OFF_FXT, out);
  k_scan <<<dim3(NBLK), dim3(256), 0, stream>>>(x, W_full, W_full1, bias, bias1,
                                                trans_b, out, ws);
}